// Round 16
// baseline (82.701 us; speedup 1.0000x reference)
//
#include <hip/hip_runtime.h>
#include <math.h>

#define NT   512
#define ROWS 128
#define NW   8
#define MAXA 320    // abs-row groups (actual 256)

static __device__ __forceinline__ unsigned f16_ru(float v) {
    // f32 -> f16 rounded toward +inf (conservative for ">= thr" band tests)
    _Float16 h = (_Float16)v;
    unsigned short b;
    __builtin_memcpy(&b, &h, 2);
    if ((float)h < v) b = (b & 0x8000) ? (unsigned short)(b - 1) : (unsigned short)(b + 1);
    return (unsigned)b;
}
static __device__ __forceinline__ float f16_lo(unsigned bits) {
    unsigned short s = (unsigned short)(bits & 0xffffu);
    _Float16 h;
    __builtin_memcpy(&h, &s, 2);
    return (float)h;
}

__global__ __launch_bounds__(NT, 4)
void e8p_quant_kernel(const float* __restrict__ X,
                      const float* __restrict__ gp,
                      const float* __restrict__ gn,
                      const int* __restrict__ pam,
                      float* __restrict__ out,
                      int N, int G)
{
#pragma clang fp contract(off)
    __shared__ float4         labsA[MAXA];   // group base vector g[0..3], f32
    __shared__ float4         labsB[MAXA];   // group base vector g[4..7], f32
    __shared__ unsigned short lmeta[MAXA];   // halfmask | (normcode<<8)
    __shared__ float          cb_bb[2][NW][ROWS];  // chunk best estimate (f32)
    __shared__ float          cb_ev[2][NW][ROWS];  // evicted-max guard (f32)
    __shared__ unsigned       cb_h [2][NW][ROWS];  // rowmax s0,s1 as f16 round-up
    __shared__ unsigned short cb_ij[2][NW][ROWS];  // row ids i0 | i1<<8 (ids<256)

    const int NG = pam[G - 1] + 1;           // group count (=256)

    // ---- stage group table from pam transitions ----
    const float4* gp4 = reinterpret_cast<const float4*>(gp);
    for (int j = threadIdx.x; j < G; j += NT) {
        int a = pam[j];
        bool st = (j == 0) || (pam[j - 1] != a);
        if (st) {
            float4 A = gp4[2 * j], B = gp4[2 * j + 1];
            labsA[a] = A;
            labsB[a] = B;
            float gv[8] = {A.x, A.y, A.z, A.w, B.x, B.y, B.z, B.w};
            int hm = 0;
#pragma unroll
            for (int k = 0; k < 7; ++k) hm |= int(fabsf(gv[k]) == 0.5f) << k;
            int nc = (int)((gn[j] - 2.0f) * 4.0f + 0.5f);   // (norm-2)*4 in [0,40]
            lmeta[a] = (unsigned short)(hm | (nc << 8));
        }
    }
    __syncthreads();

    const int lane = threadIdx.x & 63;
    const int w    = threadIdx.x >> 6;       // chunk 0..7
    const int rb   = blockIdx.x * ROWS;

    // ---- per-row prep (2 rows per lane; all waves hold the same 128 rows) ----
    float xf[2][8], xp[2][8], xm[2][8];
    int msbp[2], msbm[2], oddp[2], oddm[2];
    float DLT[2];
    const float4* x4 = reinterpret_cast<const float4*>(X);
#pragma unroll
    for (int rr = 0; rr < 2; ++rr) {
        int r = rb + lane + (rr << 6);
        int rc = (r < N) ? r : (N - 1);
        float4 a0 = x4[2 * rc], a1 = x4[2 * rc + 1];
        float xr[8] = {a0.x, a0.y, a0.z, a0.w, a1.x, a1.y, a1.z, a1.w};
        int nbp = 0, nbm = 0; float Sp = 0.f, Sm = 0.f;
#pragma unroll
        for (int k = 0; k < 8; ++k) {
            xf[rr][k] = xr[k];
            float sp = xr[k] + 0.25f, sm = xr[k] - 0.25f;
            // f32 sign == f64 sign (near-cancel exact, Sterbenz; held R3-R15)
            nbp |= int(sp < 0.f) << k;  nbm |= int(sm < 0.f) << k;
            xp[rr][k] = fabsf(sp);  xm[rr][k] = fabsf(sm);
            Sp += xp[rr][k]; Sm += xm[rr][k];
        }
        int op = __popc(nbp) & 1, om = __popc(nbm) & 1;
        if (op) xp[rr][7] = -xp[rr][7];
        if (om) xm[rr][7] = -xm[rr][7];
        oddp[rr] = op; oddm[rr] = om;
        msbp[rr] = nbp ^ (op << 7);  msbm[rr] = nbm ^ (om << 7);
        // full-scale error band applied to half-scale scores: 2x extra margin
        DLT[rr] = fmaf(3.5f * fmaxf(Sp, Sm), 3.0e-6f, 2.5e-5f);
    }

    // ring-2 + evicted-max state over GROUPS [row][pass]
    float bt[2][2], ev[2][2], s0v[2][2], s1v[2][2];
    int   i0[2][2], i1[2][2];
#pragma unroll
    for (int rr = 0; rr < 2; ++rr)
#pragma unroll
        for (int pp = 0; pp < 2; ++pp) {
            bt[rr][pp] = -3.0e38f; ev[rr][pp] = -3.0e38f;
            s0v[rr][pp] = -3.0e38f; s1v[rr][pp] = -3.0e38f;
            i0[rr][pp] = 0; i1[rr][pp] = 0;
        }

    const int Q = (NG + NW - 1) / NW;
    const int abeg = w * Q, aend = min(NG, abeg + Q);

    // ---- group scan: R14-identical body over a 32-group chunk ----
#pragma unroll 2
    for (int a = abeg; a < aend; ++a) {
        float4 ga = labsA[a], gb = labsB[a];
        int meta = __builtin_amdgcn_readfirstlane((int)lmeta[a]);  // wave-uniform
        int hm = meta & 0x7f;
        float nnh = fmaf(-0.125f, (float)(meta >> 8), -1.0f);      // = -norm/2
        float g0 = ga.x, g1 = ga.y, g2 = ga.z, g3 = ga.w;
        float g4 = gb.x, g5 = gb.y, g6 = gb.z, g7 = gb.w;
        float m2c7 = -2.0f * g7;

        float wv[2][2], rm[2][2];
#pragma unroll
        for (int rr = 0; rr < 2; ++rr) {
            float s = fmaf(xp[rr][0], g0, nnh);
            s = fmaf(xp[rr][1], g1, s); s = fmaf(xp[rr][2], g2, s);
            s = fmaf(xp[rr][3], g3, s); s = fmaf(xp[rr][4], g4, s);
            s = fmaf(xp[rr][5], g5, s); s = fmaf(xp[rr][6], g6, s);
            s = fmaf(xp[rr][7], g7, s);
            float t = fmaf(xm[rr][0], g0, nnh);
            t = fmaf(xm[rr][1], g1, t); t = fmaf(xm[rr][2], g2, t);
            t = fmaf(xm[rr][3], g3, t); t = fmaf(xm[rr][4], g4, t);
            t = fmaf(xm[rr][5], g5, t); t = fmaf(xm[rr][6], g6, t);
            t = fmaf(xm[rr][7], g7, t);
            wv[rr][0] = fmaf(m2c7, xp[rr][7], s);   // base + col7-flip term
            wv[rr][1] = fmaf(m2c7, xm[rr][7], t);
            rm[rr][0] = s; rm[rr][1] = t;
        }
#pragma unroll
        for (int i = 0; i < 7; ++i) {
            if (hm & (1 << i)) {    // wave-uniform scalar branch
                rm[0][0] = fmaxf(rm[0][0], wv[0][0] - xp[0][i]);
                rm[0][1] = fmaxf(rm[0][1], wv[0][1] - xm[0][i]);
                rm[1][0] = fmaxf(rm[1][0], wv[1][0] - xp[1][i]);
                rm[1][1] = fmaxf(rm[1][1], wv[1][1] - xm[1][i]);
            }
        }
#pragma unroll
        for (int rr = 0; rr < 2; ++rr)
#pragma unroll
            for (int pp = 0; pp < 2; ++pp) {
                float v = rm[rr][pp];
                if (v >= bt[rr][pp]) {              // in-band insert (rare)
                    ev[rr][pp] = fmaxf(ev[rr][pp], s1v[rr][pp]);
                    s1v[rr][pp] = s0v[rr][pp]; i1[rr][pp] = i0[rr][pp];
                    s0v[rr][pp] = v;           i0[rr][pp] = a;
                    bt[rr][pp] = fmaxf(bt[rr][pp], v - DLT[rr]);
                }
            }
    }

#pragma unroll
    for (int rr = 0; rr < 2; ++rr) {
        int rowL = lane + (rr << 6);
#pragma unroll
        for (int pp = 0; pp < 2; ++pp) {
            cb_bb[pp][w][rowL] = fmaxf(s0v[rr][pp], fmaxf(s1v[rr][pp], ev[rr][pp]));
            cb_ev[pp][w][rowL] = ev[rr][pp];
            cb_h [pp][w][rowL] = f16_ru(s0v[rr][pp]) | (f16_ru(s1v[rr][pp]) << 16);
            cb_ij[pp][w][rowL] = (unsigned short)(i0[rr][pp] | (i1[rr][pp] << 8));
        }
    }
    __syncthreads();

    // ---- merge + exact f64 resolve + encode: threads 0..127 ----
    const int t = threadIdx.x;
    if (t >= ROWS) return;
    const int row = rb + t;
    if (row >= N) return;
    const int rs = (t >= 64) ? 1 : 0;

    double xpd[8], xmd[8];
#pragma unroll
    for (int k = 0; k < 8; ++k) {
        double xd = (double)xf[rs][k];
        xpd[k] = fabs(xd + 0.25);   // exact in f64
        xmd[k] = fabs(xd - 0.25);
    }
    if (oddp[rs]) xpd[7] = -xpd[7];
    if (oddm[rs]) xmd[7] = -xmd[7];

    // exact full-scale evaluation of every variant of group a, ascending j
    auto evalRow = [&](int a, const double* xd, double& bd, int& brow, int& bflip) {
        float4 ga = labsA[a], gb = labsB[a];
        int meta = (int)lmeta[a];
        int hm = meta & 0x7f;
        double nd = 2.0 + 0.25 * (double)(meta >> 8);   // exact norm
        double a0=(double)ga.x, a1=(double)ga.y, a2=(double)ga.z, a3=(double)ga.w;
        double a4=(double)gb.x, a5=(double)gb.y, a6=(double)gb.z, a7=(double)gb.w;
        double s = xd[0] * a0;
        s = fma(xd[1], a1, s); s = fma(xd[2], a2, s); s = fma(xd[3], a3, s);
        s = fma(xd[4], a4, s); s = fma(xd[5], a5, s); s = fma(xd[6], a6, s);
        s = fma(xd[7], a7, s);
        double sc0 = fma(2.0, s, -nd);                  // exact
        if (sc0 > bd) { bd = sc0; brow = a; bflip = -1; }
        double sb2 = sc0 - 4.0 * (xd[7] * a7);          // exact (dyadic)
#pragma unroll
        for (int i = 0; i < 7; ++i) {
            if (hm & (1 << i)) {
                double sv = sb2 - 2.0 * xd[i];          // exact
                if (sv > bd) { bd = sv; brow = a; bflip = i; }
            }
        }
    };

    auto resolve = [&](int pp, const double* xd, int& browO, int& bflipO) {
        float B = cb_bb[pp][0][t];
#pragma unroll
        for (int w2 = 1; w2 < NW; ++w2) B = fmaxf(B, cb_bb[pp][w2][t]);
        float thr = B - DLT[rs];
        bool ok = true;
#pragma unroll
        for (int w2 = 0; w2 < NW; ++w2) ok = ok && (cb_ev[pp][w2][t] < thr);
        double bd = -1.0e300; int brow = 0, bflip = -1;
        if (ok) {
#pragma unroll
            for (int w2 = 0; w2 < NW; ++w2) {   // ascending ids: i1 older than i0
                unsigned hh = cb_h[pp][w2][t];
                unsigned ij = cb_ij[pp][w2][t];
                if (f16_lo(hh >> 16) >= thr) evalRow((int)((ij >> 8) & 0xffu), xd, bd, brow, bflip);
                if (f16_lo(hh & 0xffffu) >= thr) evalRow((int)(ij & 0xffu), xd, bd, brow, bflip);
            }
        } else {
            // sound fallback: exact scan over all groups (ascending)
            for (int a = 0; a < NG; ++a) evalRow(a, xd, bd, brow, bflip);
        }
        browO = brow; bflipO = bflip;
    };

    int prow, pflip, mrow, mflip;
    resolve(0, xpd, prow, pflip);
    resolve(1, xmd, mrow, mflip);

    double vp[8], vm[8];
    double errP, errM; int idxP, idxM;
    auto finish = [&](int brow, int bflip, double sgn_quarter, int msb, int par,
                      double* v, double& errO, int& idxO) {
#pragma clang fp contract(off)
        float4 ga = labsA[brow], gb = labsB[brow];
        float g[8] = {ga.x, ga.y, ga.z, ga.w, gb.x, gb.y, gb.z, gb.w};
        if (bflip >= 0) {
#pragma unroll
            for (int k = 0; k < 7; ++k) if (bflip == k) g[k] = -g[k];
            g[7] = -g[7];
        }
        int gneg = 0; float sumabs = 0.0f;
#pragma unroll
        for (int k = 0; k < 8; ++k) {
            gneg |= int(g[k] < 0.0f) << k;
            sumabs += fabsf(g[k]);   // exact integer in f32
        }
        double vv[8];
#pragma unroll
        for (int k = 0; k < 8; ++k) {
            unsigned u = __float_as_uint(g[k]) ^ ((((unsigned)msb >> k) & 1u) << 31);
            double val = (double)__uint_as_float(u);
            vv[k] = val;
            v[k] = val;
        }
        double d[8];
#pragma unroll
        for (int k = 0; k < 8; ++k) {
            double xs = (double)xf[rs][k] + sgn_quarter;  // exact
            d[k] = xs - vv[k];                            // exact
        }
        double q0 = d[0]*d[0], q1 = d[1]*d[1], q2 = d[2]*d[2], q3 = d[3]*d[3];
        double q4 = d[4]*d[4], q5 = d[5]*d[5], q6 = d[6]*d[6], q7 = d[7]*d[7];
        double e = ((q0 + q1) + (q2 + q3)) + ((q4 + q5) + (q6 + q7));  // np pairwise
        errO = sqrt(e);
        int godd = ((int)(sumabs + 0.5f)) & 1;   // == grid_abs_odd[abs_idx]
        int sb = gneg ^ msb;
        int mi = (((sb >> 0) & 1) ^ par)
               | (((sb >> 2) & 1) << 1)
               | (((sb >> 4) & 1) << 2)
               | (((sb >> 6) & 1) << 3)
               | (((sb >> 1) & 1) << 4)
               | (((sb >> 3) & 1) << 5)
               | (((sb >> 5) & 1) << 6)
               | ((((sb >> 7) & 1) ^ godd) << 7);
        idxO = (brow << 8) + mi;                 // pam[j] == group id
    };

    finish(prow, pflip, +0.25, msbp[rs], 1, vp, errP, idxP);
    finish(mrow, mflip, -0.25, msbm[rs], 0, vm, errM, idxM);
    bool which = errP < errM;   // strict <, matches ref

    float ov[8];
#pragma unroll
    for (int k = 0; k < 8; ++k) {
        double o = which ? (vp[k] - 0.25) : (vm[k] + 0.25);  // exact in f64
        ov[k] = (float)o;
    }
    float4* o4 = reinterpret_cast<float4*>(out + (size_t)row * 8);
    o4[0] = make_float4(ov[0], ov[1], ov[2], ov[3]);
    o4[1] = make_float4(ov[4], ov[5], ov[6], ov[7]);
    out[(size_t)N * 8 + row] = (float)(which ? idxP : idxM);  // < 2^16: exact
}

extern "C" void kernel_launch(void* const* d_in, const int* in_sizes, int n_in,
                              void* d_out, int out_size, void* d_ws, size_t ws_size,
                              hipStream_t stream)
{
    const float* X   = (const float*)d_in[0];
    const float* gp  = (const float*)d_in[1];
    const float* gn  = (const float*)d_in[2];
    const int*   pam = (const int*)d_in[3];
    float* out = (float*)d_out;

    int N = in_sizes[0] / 8;
    int G = in_sizes[1] / 8;
    int blocks = (N + ROWS - 1) / ROWS;
    e8p_quant_kernel<<<blocks, NT, 0, stream>>>(X, gp, gn, pam, out, N, G);
}

// Round 17
// 70.979 us; speedup vs baseline: 1.1651x; 1.1651x over previous
//
#include <hip/hip_runtime.h>
#include <math.h>

#define NT   256
#define ROWS 128
#define NW   4
#define MAXA 320   // abs-row groups (actual 256)

static __device__ __forceinline__ unsigned f16_ru(float v) {
    // f32 -> f16 rounded toward +inf (conservative for ">= thr" band tests)
    _Float16 h = (_Float16)v;
    unsigned short b;
    __builtin_memcpy(&b, &h, 2);
    if ((float)h < v) b = (b & 0x8000) ? (unsigned short)(b - 1) : (unsigned short)(b + 1);
    return (unsigned)b;
}
static __device__ __forceinline__ float f16_lo(unsigned bits) {
    unsigned short s = (unsigned short)(bits & 0xffffu);
    _Float16 h;
    __builtin_memcpy(&h, &s, 2);
    return (float)h;
}

__global__ __launch_bounds__(NT, 4)
void e8p_quant_kernel(const float* __restrict__ X,
                      const float* __restrict__ gp,
                      const float* __restrict__ gn,
                      const int* __restrict__ pam,
                      float* __restrict__ out,
                      int N, int G)
{
#pragma clang fp contract(off)
    __shared__ float4         labsA[MAXA];   // group base vector g[0..3], f32
    __shared__ float4         labsB[MAXA];   // group base vector g[4..7], f32
    __shared__ unsigned short lmeta[MAXA];   // halfmask | (normcode<<8)
    __shared__ float    cb_bb[2][NW][ROWS];  // chunk best estimate (f32)
    __shared__ float    cb_ev[2][NW][ROWS];  // evicted-max guard (f32)
    __shared__ unsigned cb_h [2][NW][ROWS];  // rowmax s0,s1 as f16 round-up
    __shared__ unsigned cb_ij[2][NW][ROWS];  // row ids i0 | i1<<16

    const int NG = pam[G - 1] + 1;           // group count (=256)

    // ---- stage group table from pam transitions ----
    const float4* gp4 = reinterpret_cast<const float4*>(gp);
    for (int j = threadIdx.x; j < G; j += NT) {
        int a = pam[j];
        bool st = (j == 0) || (pam[j - 1] != a);
        if (st) {
            float4 A = gp4[2 * j], B = gp4[2 * j + 1];
            labsA[a] = A;
            labsB[a] = B;
            float gv[8] = {A.x, A.y, A.z, A.w, B.x, B.y, B.z, B.w};
            int hm = 0;
#pragma unroll
            for (int k = 0; k < 7; ++k) hm |= int(fabsf(gv[k]) == 0.5f) << k;
            int nc = (int)((gn[j] - 2.0f) * 4.0f + 0.5f);   // (norm-2)*4 in [0,40]
            lmeta[a] = (unsigned short)(hm | (nc << 8));
        }
    }
    __syncthreads();

    const int lane = threadIdx.x & 63;
    const int w    = threadIdx.x >> 6;
    const int rb   = blockIdx.x * ROWS;

    // ---- per-row prep (2 rows per lane) ----
    float xf[2][8], xp[2][8], xm[2][8];
    int msbp[2], msbm[2], oddp[2], oddm[2];
    float DLT[2];
    const float4* x4 = reinterpret_cast<const float4*>(X);
#pragma unroll
    for (int rr = 0; rr < 2; ++rr) {
        int r = rb + lane + (rr << 6);
        int rc = (r < N) ? r : (N - 1);
        float4 a0 = x4[2 * rc], a1 = x4[2 * rc + 1];
        float xr[8] = {a0.x, a0.y, a0.z, a0.w, a1.x, a1.y, a1.z, a1.w};
        int nbp = 0, nbm = 0; float Sp = 0.f, Sm = 0.f;
#pragma unroll
        for (int k = 0; k < 8; ++k) {
            xf[rr][k] = xr[k];
            float sp = xr[k] + 0.25f, sm = xr[k] - 0.25f;
            // f32 sign == f64 sign (near-cancel exact, Sterbenz; held R3-R16)
            nbp |= int(sp < 0.f) << k;  nbm |= int(sm < 0.f) << k;
            xp[rr][k] = fabsf(sp);  xm[rr][k] = fabsf(sm);
            Sp += xp[rr][k]; Sm += xm[rr][k];
        }
        int op = __popc(nbp) & 1, om = __popc(nbm) & 1;
        if (op) xp[rr][7] = -xp[rr][7];
        if (om) xm[rr][7] = -xm[rr][7];
        oddp[rr] = op; oddm[rr] = om;
        msbp[rr] = nbp ^ (op << 7);  msbm[rr] = nbm ^ (om << 7);
        // full-scale error band applied to half-scale scores: 2x extra margin
        DLT[rr] = fmaf(3.5f * fmaxf(Sp, Sm), 3.0e-6f, 2.5e-5f);
    }

    // ring-2 + evicted-max state over GROUPS [row][pass]
    float bt[2][2], ev[2][2], s0v[2][2], s1v[2][2];
    int   i0[2][2], i1[2][2];
#pragma unroll
    for (int rr = 0; rr < 2; ++rr)
#pragma unroll
        for (int pp = 0; pp < 2; ++pp) {
            bt[rr][pp] = -3.0e38f; ev[rr][pp] = -3.0e38f;
            s0v[rr][pp] = -3.0e38f; s1v[rr][pp] = -3.0e38f;
            i0[rr][pp] = 0; i1[rr][pp] = 0;
        }

    const int Q = (NG + NW - 1) / NW;
    const int abeg = w * Q, aend = min(NG, abeg + Q);

    // ---- group scan: half-scale base score + rank-1 variant maxima ----
#pragma unroll 2
    for (int a = abeg; a < aend; ++a) {
        float4 ga = labsA[a], gb = labsB[a];
        int meta = __builtin_amdgcn_readfirstlane((int)lmeta[a]);  // wave-uniform
        int hm = meta & 0x7f;
        float nnh = fmaf(-0.125f, (float)(meta >> 8), -1.0f);      // = -norm/2
        float g0 = ga.x, g1 = ga.y, g2 = ga.z, g3 = ga.w;
        float g4 = gb.x, g5 = gb.y, g6 = gb.z, g7 = gb.w;
        float m2c7 = -2.0f * g7;

        float sc[2][2], wv[2][2], rm[2][2];
#pragma unroll
        for (int rr = 0; rr < 2; ++rr) {
            float s = fmaf(xp[rr][0], g0, nnh);
            s = fmaf(xp[rr][1], g1, s); s = fmaf(xp[rr][2], g2, s);
            s = fmaf(xp[rr][3], g3, s); s = fmaf(xp[rr][4], g4, s);
            s = fmaf(xp[rr][5], g5, s); s = fmaf(xp[rr][6], g6, s);
            s = fmaf(xp[rr][7], g7, s);
            sc[rr][0] = s;
            float t = fmaf(xm[rr][0], g0, nnh);
            t = fmaf(xm[rr][1], g1, t); t = fmaf(xm[rr][2], g2, t);
            t = fmaf(xm[rr][3], g3, t); t = fmaf(xm[rr][4], g4, t);
            t = fmaf(xm[rr][5], g5, t); t = fmaf(xm[rr][6], g6, t);
            t = fmaf(xm[rr][7], g7, t);
            sc[rr][1] = t;
            wv[rr][0] = fmaf(m2c7, xp[rr][7], s);   // base + col7-flip term
            wv[rr][1] = fmaf(m2c7, xm[rr][7], t);
            rm[rr][0] = s; rm[rr][1] = t;
        }
#pragma unroll
        for (int i = 0; i < 7; ++i) {
            if (hm & (1 << i)) {    // wave-uniform scalar branch
                rm[0][0] = fmaxf(rm[0][0], wv[0][0] - xp[0][i]);
                rm[0][1] = fmaxf(rm[0][1], wv[0][1] - xm[0][i]);
                rm[1][0] = fmaxf(rm[1][0], wv[1][0] - xp[1][i]);
                rm[1][1] = fmaxf(rm[1][1], wv[1][1] - xm[1][i]);
            }
        }
#pragma unroll
        for (int rr = 0; rr < 2; ++rr)
#pragma unroll
            for (int pp = 0; pp < 2; ++pp) {
                float v = rm[rr][pp];
                if (v >= bt[rr][pp]) {              // in-band insert (rare)
                    ev[rr][pp] = fmaxf(ev[rr][pp], s1v[rr][pp]);
                    s1v[rr][pp] = s0v[rr][pp]; i1[rr][pp] = i0[rr][pp];
                    s0v[rr][pp] = v;           i0[rr][pp] = a;
                    bt[rr][pp] = fmaxf(bt[rr][pp], v - DLT[rr]);
                }
            }
    }

#pragma unroll
    for (int rr = 0; rr < 2; ++rr) {
        int rowL = lane + (rr << 6);
#pragma unroll
        for (int pp = 0; pp < 2; ++pp) {
            cb_bb[pp][w][rowL] = fmaxf(s0v[rr][pp], fmaxf(s1v[rr][pp], ev[rr][pp]));
            cb_ev[pp][w][rowL] = ev[rr][pp];
            cb_h [pp][w][rowL] = f16_ru(s0v[rr][pp]) | (f16_ru(s1v[rr][pp]) << 16);
            cb_ij[pp][w][rowL] = (unsigned)i0[rr][pp] | ((unsigned)i1[rr][pp] << 16);
        }
    }
    __syncthreads();

    // ---- merge + exact f64 resolve + encode: threads 0..127 ----
    const int t = threadIdx.x;
    if (t >= ROWS) return;
    const int row = rb + t;
    if (row >= N) return;
    const int rs = (t >= 64) ? 1 : 0;

    double xpd[8], xmd[8];
#pragma unroll
    for (int k = 0; k < 8; ++k) {
        double xd = (double)xf[rs][k];
        xpd[k] = fabs(xd + 0.25);   // exact in f64
        xmd[k] = fabs(xd - 0.25);
    }
    if (oddp[rs]) xpd[7] = -xpd[7];
    if (oddm[rs]) xmd[7] = -xmd[7];

    // exact full-scale evaluation of every variant of group a, ascending j
    auto evalRow = [&](int a, const double* xd, double& bd, int& brow, int& bflip) {
        float4 ga = labsA[a], gb = labsB[a];
        int meta = (int)lmeta[a];
        int hm = meta & 0x7f;
        double nd = 2.0 + 0.25 * (double)(meta >> 8);   // exact norm
        double a0=(double)ga.x, a1=(double)ga.y, a2=(double)ga.z, a3=(double)ga.w;
        double a4=(double)gb.x, a5=(double)gb.y, a6=(double)gb.z, a7=(double)gb.w;
        double s = xd[0] * a0;
        s = fma(xd[1], a1, s); s = fma(xd[2], a2, s); s = fma(xd[3], a3, s);
        s = fma(xd[4], a4, s); s = fma(xd[5], a5, s); s = fma(xd[6], a6, s);
        s = fma(xd[7], a7, s);
        double sc0 = fma(2.0, s, -nd);                  // exact
        if (sc0 > bd) { bd = sc0; brow = a; bflip = -1; }
        double sb2 = sc0 - 4.0 * (xd[7] * a7);          // exact (dyadic)
#pragma unroll
        for (int i = 0; i < 7; ++i) {
            if (hm & (1 << i)) {
                double sv = sb2 - 2.0 * xd[i];          // exact
                if (sv > bd) { bd = sv; brow = a; bflip = i; }
            }
        }
    };

    auto resolve = [&](int pp, const double* xd, int& browO, int& bflipO) {
        float B = fmaxf(fmaxf(cb_bb[pp][0][t], cb_bb[pp][1][t]),
                        fmaxf(cb_bb[pp][2][t], cb_bb[pp][3][t]));
        float thr = B - DLT[rs];
        bool ok = (cb_ev[pp][0][t] < thr) && (cb_ev[pp][1][t] < thr) &&
                  (cb_ev[pp][2][t] < thr) && (cb_ev[pp][3][t] < thr);
        double bd = -1.0e300; int brow = 0, bflip = -1;
        if (ok) {
#pragma unroll
            for (int w2 = 0; w2 < NW; ++w2) {   // ascending rows: i1 older than i0
                unsigned hh = cb_h[pp][w2][t], ij = cb_ij[pp][w2][t];
                if (f16_lo(hh >> 16) >= thr) evalRow((int)(ij >> 16), xd, bd, brow, bflip);
                if (f16_lo(hh & 0xffffu) >= thr) evalRow((int)(ij & 0xffffu), xd, bd, brow, bflip);
            }
        } else {
            // sound fallback: exact scan over all groups (ascending j)
            for (int a = 0; a < NG; ++a) evalRow(a, xd, bd, brow, bflip);
        }
        browO = brow; bflipO = bflip;
    };

    int prow, pflip, mrow, mflip;
    resolve(0, xpd, prow, pflip);
    resolve(1, xmd, mrow, mflip);

    double vp[8], vm[8];
    double errP, errM; int idxP, idxM;
    auto finish = [&](int brow, int bflip, double sgn_quarter, int msb, int par,
                      double* v, double& errO, int& idxO) {
#pragma clang fp contract(off)
        float4 ga = labsA[brow], gb = labsB[brow];
        float g[8] = {ga.x, ga.y, ga.z, ga.w, gb.x, gb.y, gb.z, gb.w};
        if (bflip >= 0) {
#pragma unroll
            for (int k = 0; k < 7; ++k) if (bflip == k) g[k] = -g[k];
            g[7] = -g[7];
        }
        int gneg = 0; float sumabs = 0.0f;
#pragma unroll
        for (int k = 0; k < 8; ++k) {
            gneg |= int(g[k] < 0.0f) << k;
            sumabs += fabsf(g[k]);   // exact integer in f32
        }
        double vv[8];
#pragma unroll
        for (int k = 0; k < 8; ++k) {
            unsigned u = __float_as_uint(g[k]) ^ ((((unsigned)msb >> k) & 1u) << 31);
            double val = (double)__uint_as_float(u);
            vv[k] = val;
            v[k] = val;
        }
        double d[8];
#pragma unroll
        for (int k = 0; k < 8; ++k) {
            double xs = (double)xf[rs][k] + sgn_quarter;  // exact
            d[k] = xs - vv[k];                            // exact
        }
        double q0 = d[0]*d[0], q1 = d[1]*d[1], q2 = d[2]*d[2], q3 = d[3]*d[3];
        double q4 = d[4]*d[4], q5 = d[5]*d[5], q6 = d[6]*d[6], q7 = d[7]*d[7];
        double e = ((q0 + q1) + (q2 + q3)) + ((q4 + q5) + (q6 + q7));  // np pairwise
        errO = sqrt(e);
        int godd = ((int)(sumabs + 0.5f)) & 1;   // == grid_abs_odd[abs_idx]
        int sb = gneg ^ msb;
        int mi = (((sb >> 0) & 1) ^ par)
               | (((sb >> 2) & 1) << 1)
               | (((sb >> 4) & 1) << 2)
               | (((sb >> 6) & 1) << 3)
               | (((sb >> 1) & 1) << 4)
               | (((sb >> 3) & 1) << 5)
               | (((sb >> 5) & 1) << 6)
               | ((((sb >> 7) & 1) ^ godd) << 7);
        idxO = (brow << 8) + mi;                 // pam[j] == group id
    };

    finish(prow, pflip, +0.25, msbp[rs], 1, vp, errP, idxP);
    finish(mrow, mflip, -0.25, msbm[rs], 0, vm, errM, idxM);
    bool which = errP < errM;   // strict <, matches ref

    float ov[8];
#pragma unroll
    for (int k = 0; k < 8; ++k) {
        double o = which ? (vp[k] - 0.25) : (vm[k] + 0.25);  // exact in f64
        ov[k] = (float)o;
    }
    float4* o4 = reinterpret_cast<float4*>(out + (size_t)row * 8);
    o4[0] = make_float4(ov[0], ov[1], ov[2], ov[3]);
    o4[1] = make_float4(ov[4], ov[5], ov[6], ov[7]);
    out[(size_t)N * 8 + row] = (float)(which ? idxP : idxM);  // < 2^16: exact
}

extern "C" void kernel_launch(void* const* d_in, const int* in_sizes, int n_in,
                              void* d_out, int out_size, void* d_ws, size_t ws_size,
                              hipStream_t stream)
{
    const float* X   = (const float*)d_in[0];
    const float* gp  = (const float*)d_in[1];
    const float* gn  = (const float*)d_in[2];
    const int*   pam = (const int*)d_in[3];
    float* out = (float*)d_out;

    int N = in_sizes[0] / 8;
    int G = in_sizes[1] / 8;
    int blocks = (N + ROWS - 1) / ROWS;
    e8p_quant_kernel<<<blocks, NT, 0, stream>>>(X, gp, gn, pam, out, N, G);
}